// Round 1
// baseline (520.590 us; speedup 1.0000x reference)
//
#include <hip/hip_runtime.h>
#include <stdint.h>
#include <stddef.h>

#define B_ROWS 16384
#define DIN 1024
#define DOUT 1024
#define KDIM 2048   // DIN + DOUT

#define BM 256      // rows per block
#define BNP 256     // packed cols per block = 4 groups x (4 gates x 16 cols)
#define BK 64       // K per tile; 32 K-tiles total

typedef __bf16 bf16x8 __attribute__((ext_vector_type(8)));
typedef float floatx4 __attribute__((ext_vector_type(4)));

__device__ __forceinline__ unsigned short f2bf(float f) {
  unsigned int u = __float_as_uint(f);
  u += 0x7fffu + ((u >> 16) & 1u);   // round-to-nearest-even
  return (unsigned short)(u >> 16);
}

__device__ __forceinline__ void async16(const void* g, void* l) {
  __builtin_amdgcn_global_load_lds(
      (__attribute__((address_space(1))) void*)(g),
      (__attribute__((address_space(3))) void*)(l), 16, 0, 0);
}

__device__ __forceinline__ float sigmoid_f(float x) {
  return 1.0f / (1.0f + __expf(-x));
}
__device__ __forceinline__ float tanh_f(float x) {
  return 2.0f / (1.0f + __expf(-2.0f * x)) - 1.0f;
}

// ---------------- prep (single launch): cast X + transpose/pack W ----------
// blocks [0, 32768): cast & concat X = [inputs | hist] -> bf16 16384 x 2048
// blocks [32768, 40960): transpose W into gate-packed n-major layout:
//   packed row np = (n>>4)*64 + g*16 + (n&15), row length KDIM (k-major).
//   One GEMM wave (64 packed rows) = all 4 gates for the same 16 cols.
//   z = 2*g + part; part0 = Wx (k 0..1023), part1 = Wh (k 1024..2047)
__global__ void prep_kernel(
    const float* __restrict__ inp, const float* __restrict__ hist,
    const float* __restrict__ s0, const float* __restrict__ s1,
    const float* __restrict__ s2, const float* __restrict__ s3,
    const float* __restrict__ s4, const float* __restrict__ s5,
    const float* __restrict__ s6, const float* __restrict__ s7,
    unsigned short* __restrict__ xb, unsigned short* __restrict__ wt) {
  __shared__ float tile[32][33];
  const int tid = threadIdx.x;
  if (blockIdx.x < 32768) {
    int idx = blockIdx.x * 256 + tid;           // one float4 per thread
    const int per = B_ROWS * DIN / 4;
    const float* src;
    int colOff;
    int i = idx;
    if (i < per) { src = inp; colOff = 0; }
    else         { src = hist; colOff = DIN; i -= per; }
    int e = i * 4;
    int row = e >> 10;
    int col = e & 1023;
    const float4 v = *(const float4*)(src + (size_t)row * 1024 + col);
    ushort4 o;
    o.x = f2bf(v.x); o.y = f2bf(v.y); o.z = f2bf(v.z); o.w = f2bf(v.w);
    *(ushort4*)(xb + (size_t)row * KDIM + colOff + col) = o;
    return;
  }
  const int bb = blockIdx.x - 32768;            // 0..8191 = 32 x 32 x 8
  const int bx = bb & 31, by = (bb >> 5) & 31, z = bb >> 10;
  const float* src;
  switch (z) {
    case 0: src = s0; break; case 1: src = s1; break;
    case 2: src = s2; break; case 3: src = s3; break;
    case 4: src = s4; break; case 5: src = s5; break;
    case 6: src = s6; break; default: src = s7; break;
  }
  const int g = z >> 1, part = z & 1;
  const int tx = tid & 31, ty = tid >> 5;       // 32 x 8
  const int n0 = bx * 32, k0 = by * 32;
#pragma unroll
  for (int j = 0; j < 32; j += 8)
    tile[ty + j][tx] = src[(size_t)(k0 + ty + j) * DOUT + n0 + tx];
  __syncthreads();
#pragma unroll
  for (int j = 0; j < 32; j += 8) {
    const int n = n0 + ty + j;
    const int np = ((n >> 4) << 6) + g * 16 + (n & 15);
    wt[(size_t)np * KDIM + part * DIN + k0 + tx] = f2bf(tile[tx][ty + j]);
  }
}

// ---------------- fused 4-gate GEMM + LSTM epilogue, 8-phase pipeline ------
// 256x256(packed) tile, 512 thr / 8 waves (2M x 4N), wave tile 128 x 64.
// LDS regions: As/Bs[buf][khalf][256][32] bf16; chunk-XOR swizzle
//   slot(row,u) holds global 8-elem chunk u ^ ((row>>1)&3)  (2-way banks = free).
// Phase p of K-tile t (buf = t&1):
//   P0: ds A[m0-3]k0 + B[all]k0   | issue (A,k1,t+1)
//   P1: ds A[m4-7]k0 (B in regs)  | issue (B,k0,t+2) | vmcnt(10)
//   P2: ds A[m0-3]k1 + B[all]k1   | issue (A,k0,t+2)
//   P3: ds A[m4-7]k1              | issue (B,k1,t+2) | vmcnt(10)
// Each issue targets a region whose last reader passed the previous barrier.
// vmcnt(10) = 5 units x 2 loads younger than the unit being certified.
#define FENCE() __builtin_amdgcn_sched_barrier(0)
#define BAR() do { FENCE(); __builtin_amdgcn_s_barrier(); FENCE(); } while (0)
#define WAITV(N) asm volatile("s_waitcnt vmcnt(" #N ")" ::: "memory")
#define REGOFF(BUF, KH) (((BUF) * 2 + (KH)) << 13)

#define STAGE_A(BUF, KH, KT) do {                                          \
    unsigned short* d_ = As + REGOFF(BUF, KH) + tid * 8;                   \
    async16(agA + (KT) + (KH) * 32, d_);                                   \
    async16(agA + 128 * KDIM + (KT) + (KH) * 32, d_ + 4096);               \
  } while (0)
#define STAGE_B(BUF, KH, KT) do {                                          \
    unsigned short* d_ = Bs + REGOFF(BUF, KH) + tid * 8;                   \
    async16(agB + (KT) + (KH) * 32, d_);                                   \
    async16(agB + 128 * KDIM + (KT) + (KH) * 32, d_ + 4096);               \
  } while (0)
#define LDA4(BUF, KK, MH) do {                                             \
    const unsigned short* b_ = As + REGOFF(BUF, KK) + (MH) * 2048 + aoff;  \
    _Pragma("unroll")                                                      \
    for (int mi = 0; mi < 4; ++mi)                                         \
      av[mi] = *(const bf16x8*)(b_ + mi * 512);                            \
  } while (0)
#define LDB4(BUF, KK) do {                                                 \
    const unsigned short* b_ = Bs + REGOFF(BUF, KK) + boff;                \
    _Pragma("unroll")                                                      \
    for (int ni = 0; ni < 4; ++ni)                                         \
      bv[ni] = *(const bf16x8*)(b_ + ni * 512);                            \
  } while (0)
#define MFMA16(MH) do {                                                    \
    __builtin_amdgcn_s_setprio(1);                                         \
    _Pragma("unroll")                                                      \
    for (int mi = 0; mi < 4; ++mi)                                         \
      _Pragma("unroll")                                                    \
      for (int ni = 0; ni < 4; ++ni)                                       \
        acc[(MH) * 4 + mi][ni] = __builtin_amdgcn_mfma_f32_16x16x32_bf16(  \
            av[mi], bv[ni], acc[(MH) * 4 + mi][ni], 0, 0, 0);              \
    __builtin_amdgcn_s_setprio(0);                                         \
  } while (0)

__global__ __launch_bounds__(512, 2) void lstm_fused_kernel(
    const unsigned short* __restrict__ Xb,    // 16384 x 2048 bf16
    const unsigned short* __restrict__ Wt2,   // 4096 x 2048 bf16 packed
    const float* __restrict__ b_f, const float* __restrict__ b_i,
    const float* __restrict__ b_o, const float* __restrict__ b_c,
    const int* __restrict__ carousel,
    float* __restrict__ out) {                // h (16384x1024) then c
  __shared__ unsigned short As[4 * 256 * 32];   // [buf][kh][256][32] = 64 KiB
  __shared__ unsigned short Bs[4 * 256 * 32];   // 64 KiB

  const int tid  = threadIdx.x;
  const int lane = tid & 63;
  const int wave = tid >> 6;
  const int wr   = wave >> 2;               // 0..1  (M half)
  const int wc   = wave & 3;                // 0..3  (N group)
  const int m16  = lane & 15;
  const int quad = lane >> 4;
  const int ua   = quad ^ ((m16 >> 1) & 3); // read-side chunk swizzle
  const int bm   = blockIdx.y * BM;
  const int cg   = blockIdx.x;              // 64-orig-col block

  const unsigned short* Wp = Wt2 + (size_t)cg * BNP * KDIM;

  // epilogue scalars loaded BEFORE any staging so they never perturb vmcnt
  const int col = cg * 64 + wc * 16 + m16;
  const float bfv = b_f[col], biv = b_i[col], bov = b_o[col], bcv = b_c[col];
  const float cf  = (float)carousel[0];
  FENCE();

  // staging addresses: unit = 256 rows x 32 cols (16 KiB), 2 loads/thread
  const int srow   = tid >> 2;                            // 0..127
  const int schunk = (tid & 3) ^ ((srow >> 1) & 3);       // source chunk
  const unsigned short* agA = Xb + (size_t)(bm + srow) * KDIM + schunk * 8;
  const unsigned short* agB = Wp + (size_t)srow * KDIM + schunk * 8;

  const int aoff = (wr * 128 + m16) * 32 + ua * 8;        // ushort offsets
  const int boff = (wc * 64 + m16) * 32 + ua * 8;

  floatx4 acc[8][4];
#pragma unroll
  for (int mi = 0; mi < 8; ++mi)
#pragma unroll
    for (int ni = 0; ni < 4; ++ni)
      acc[mi][ni] = (floatx4){0.f, 0.f, 0.f, 0.f};

  bf16x8 av[4], bv[4];

  // prologue: units in steady-state order; vmcnt(10) certifies (B,k0,0),(A,k0,0)
  STAGE_B(0, 0, 0);     // U1 (B,k0,0)
  STAGE_A(0, 0, 0);     // U2 (A,k0,0)
  STAGE_B(0, 1, 0);     // U3 (B,k1,0)
  STAGE_A(0, 1, 0);     // U4 (A,k1,0)
  STAGE_B(1, 0, 64);    // U5 (B,k0,1)
  STAGE_A(1, 0, 64);    // U6 (A,k0,1)
  STAGE_B(1, 1, 64);    // U7 (B,k1,1)
  WAITV(10);
  BAR();

#pragma unroll 1
  for (int p = 0; p < 15; ++p) {            // tiles 0..29, pairs
    const int kt = p * 128;
    // ---- tile 2p (buf 0, KT = kt) ----
    LDA4(0, 0, 0); LDB4(0, 0);
    STAGE_A(1, 1, kt + 64);                 // (A,k1,t+1)
    BAR(); MFMA16(0); BAR();
    LDA4(0, 0, 1);
    STAGE_B(0, 0, kt + 128);                // (B,k0,t+2)
    WAITV(10); BAR(); MFMA16(1); BAR();
    LDA4(0, 1, 0); LDB4(0, 1);
    STAGE_A(0, 0, kt + 128);                // (A,k0,t+2)
    BAR(); MFMA16(0); BAR();
    LDA4(0, 1, 1);
    STAGE_B(0, 1, kt + 128);                // (B,k1,t+2)
    WAITV(10); BAR(); MFMA16(1); BAR();
    // ---- tile 2p+1 (buf 1, KT = kt + 64) ----
    LDA4(1, 0, 0); LDB4(1, 0);
    STAGE_A(0, 1, kt + 128);                // (A,k1,t+1)
    BAR(); MFMA16(0); BAR();
    LDA4(1, 0, 1);
    STAGE_B(1, 0, kt + 192);                // (B,k0,t+2)
    WAITV(10); BAR(); MFMA16(1); BAR();
    LDA4(1, 1, 0); LDB4(1, 1);
    STAGE_A(1, 0, kt + 192);                // (A,k0,t+2)
    BAR(); MFMA16(0); BAR();
    LDA4(1, 1, 1);
    STAGE_B(1, 1, kt + 192);                // (B,k1,t+2)
    WAITV(10); BAR(); MFMA16(1); BAR();
  }

  // ---- tile 30 (buf 0, KT = 1920): tail waits 8 -> 4 ----
  LDA4(0, 0, 0); LDB4(0, 0);
  STAGE_A(1, 1, 1984);                      // (A,k1,31) - last unit
  BAR(); MFMA16(0); BAR();
  LDA4(0, 0, 1);
  WAITV(8); BAR(); MFMA16(1); BAR();
  LDA4(0, 1, 0); LDB4(0, 1);
  BAR(); MFMA16(0); BAR();
  LDA4(0, 1, 1);
  WAITV(4); BAR(); MFMA16(1); BAR();
  // ---- tile 31 (buf 1, KT = 1984): final drain ----
  LDA4(1, 0, 0); LDB4(1, 0);
  BAR(); MFMA16(0); BAR();
  LDA4(1, 0, 1);
  WAITV(0); BAR(); MFMA16(1); BAR();
  LDA4(1, 1, 0); LDB4(1, 1);
  MFMA16(0);
  LDA4(1, 1, 1);
  MFMA16(1);

  // epilogue: n-frag ni == gate (f,i,o,c) for this wave's 16-col group
  const int rbase = bm + wr * 128 + quad * 4;
#pragma unroll
  for (int mi = 0; mi < 8; ++mi) {
#pragma unroll
    for (int r = 0; r < 4; ++r) {
      const int row = rbase + mi * 16 + r;
      const float f = sigmoid_f(acc[mi][0][r] + bfv);
      const float i = sigmoid_f(acc[mi][1][r] + biv);
      const float o = sigmoid_f(acc[mi][2][r] + bov);
      const float g = tanh_f   (acc[mi][3][r] + bcv);
      const float c = f * cf + i * g;
      const float h = o * c;
      out[(size_t)row * DOUT + col] = h;
      out[(size_t)(B_ROWS * DOUT) + (size_t)row * DOUT + col] = c;
    }
  }
}

extern "C" void kernel_launch(void* const* d_in, const int* in_sizes, int n_in,
                              void* d_out, int out_size, void* d_ws, size_t ws_size,
                              hipStream_t stream) {
  const float* inputs = (const float*)d_in[0];
  const float* hist   = (const float*)d_in[1];
  const int* carousel = (const int*)d_in[2];
  const float* Wfx = (const float*)d_in[3];
  const float* Wfh = (const float*)d_in[4];
  const float* bfv = (const float*)d_in[5];
  const float* Wix = (const float*)d_in[6];
  const float* Wih = (const float*)d_in[7];
  const float* biv = (const float*)d_in[8];
  const float* Wox = (const float*)d_in[9];
  const float* Woh = (const float*)d_in[10];
  const float* bov = (const float*)d_in[11];
  const float* Wcx = (const float*)d_in[12];
  const float* Wch = (const float*)d_in[13];
  const float* bcv = (const float*)d_in[14];

  unsigned short* Xb  = (unsigned short*)d_ws;               // 64 MB
  unsigned short* Wt2 = Xb + (size_t)B_ROWS * KDIM;          // 16 MB

  prep_kernel<<<40960, 256, 0, stream>>>(
      inputs, hist, Wfx, Wfh, Wix, Wih, Wox, Woh, Wcx, Wch, Xb, Wt2);

  dim3 grid(16, B_ROWS / BM);                                // 16 x 64 = 1024
  lstm_fused_kernel<<<grid, 512, 0, stream>>>(
      Xb, Wt2, bfv, biv, bov, bcv, carousel, (float*)d_out);
}